// Round 6
// baseline (462.240 us; speedup 1.0000x reference)
//
#include <hip/hip_runtime.h>
#include <hip/hip_bf16.h>

#define CIN 128
#define CO  64

typedef __attribute__((ext_vector_type(8))) short shortx8;
typedef __attribute__((ext_vector_type(4))) float floatx4;

__device__ __forceinline__ float lrelu(float x, float s) { return x > 0.f ? x : x * s; }

__device__ __forceinline__ short f2bs(float f) {
    union { __hip_bfloat16 h; short s; } u;
    u.h = __float2bfloat16(f);
    return u.s;
}

__device__ __forceinline__ shortx8 pack8(const float4& a, const float4& b) {
    shortx8 r;
    r[0] = f2bs(a.x); r[1] = f2bs(a.y); r[2] = f2bs(a.z); r[3] = f2bs(a.w);
    r[4] = f2bs(b.x); r[5] = f2bs(b.y); r[6] = f2bs(b.z); r[7] = f2bs(b.w);
    return r;
}

// unpack bfloat162 dword -> 2 floats (2 VALU ops)
__device__ __forceinline__ float2 bf2x(unsigned p) {
    float2 r;
    r.x = __uint_as_float(p << 16);
    r.y = __uint_as_float(p & 0xffff0000u);
    return r;
}

// K0: emb-part of attention scores.
__global__ __launch_bounds__(256) void k_escore(
    const float* __restrict__ emb, const float* __restrict__ aei, const float* __restrict__ aej,
    float* __restrict__ sie, float* __restrict__ sje, int N)
{
    int lane = threadIdx.x & 63;
    int slot = lane & 15, grp = lane >> 4;
    float4 vi = ((const float4*)aei)[slot];
    float4 vj = ((const float4*)aej)[slot];
    int w = blockIdx.x * 4 + (threadIdx.x >> 6);
    int nwaves = gridDim.x * 4;
    int groups = (N + 3) >> 2;
    for (int g = w; g < groups; g += nwaves) {
        int n = g * 4 + grp;
        float pi = 0.f, pj = 0.f;
        if (n < N) {
            float4 e = ((const float4*)(emb + (size_t)n * CO))[slot];
            pi = e.x * vi.x + e.y * vi.y + e.z * vi.z + e.w * vi.w;
            pj = e.x * vj.x + e.y * vj.y + e.z * vj.z + e.w * vj.w;
        }
#pragma unroll
        for (int off = 1; off < 16; off <<= 1) {
            pi += __shfl_xor(pi, off);
            pj += __shfl_xor(pj, off);
        }
        if (slot == 0 && n < N) { sie[n] = pi; sje[n] = pj; }
    }
}

// K1: MFMA GEMM xl = x@W^T + b (16x16x32 bf16), fused score dots + bf16 tile write.
__global__ __launch_bounds__(256) void k_gemm(
    const float* __restrict__ x, const float* __restrict__ W,
    const float* __restrict__ lb, const float* __restrict__ ai, const float* __restrict__ aj,
    const float* __restrict__ sie, const float* __restrict__ sje,
    __hip_bfloat16* __restrict__ xlb, float* __restrict__ s_i, float* __restrict__ s_j, int N)
{
    __shared__ __hip_bfloat16 tile[4][16 * 72];
    const int lane = threadIdx.x & 63;
    const int wv   = threadIdx.x >> 6;
    const int col0 = lane & 15;
    const int quad = lane >> 4;

    shortx8 wf[4][4];
#pragma unroll
    for (int cg = 0; cg < 4; ++cg)
#pragma unroll
        for (int ks = 0; ks < 4; ++ks) {
            const float* wp = W + (cg * 16 + col0) * CIN + ks * 32 + quad * 8;
            float4 w0 = *(const float4*)wp;
            float4 w1 = *(const float4*)(wp + 4);
            wf[cg][ks] = pack8(w0, w1);
        }
    float biasv[4], aiv[4], ajv[4];
#pragma unroll
    for (int cg = 0; cg < 4; ++cg) {
        biasv[cg] = lb[cg * 16 + col0];
        aiv[cg]   = ai[cg * 16 + col0];
        ajv[cg]   = aj[cg * 16 + col0];
    }

    int tiles = (N + 15) >> 4;
    for (int t = blockIdx.x * 4 + wv; t < tiles; t += gridDim.x * 4) {
        int n0 = t * 16;
        int arow = n0 + col0; if (arow > N - 1) arow = N - 1;
        const float* xp = x + (size_t)arow * CIN + quad * 8;
        float4 a0[4], a1[4];
#pragma unroll
        for (int ks = 0; ks < 4; ++ks) {
            a0[ks] = *(const float4*)(xp + ks * 32);
            a1[ks] = *(const float4*)(xp + ks * 32 + 4);
        }
        floatx4 z = {0.f, 0.f, 0.f, 0.f};
        floatx4 acc[4] = {z, z, z, z};
#pragma unroll
        for (int ks = 0; ks < 4; ++ks) {
            shortx8 af = pack8(a0[ks], a1[ks]);
#pragma unroll
            for (int cg = 0; cg < 4; ++cg)
                acc[cg] = __builtin_amdgcn_mfma_f32_16x16x32_bf16(af, wf[cg][ks], acc[cg], 0, 0, 0);
        }
        float pi[4] = {0, 0, 0, 0}, pj[4] = {0, 0, 0, 0};
        __hip_bfloat16* tp = tile[wv];
#pragma unroll
        for (int cg = 0; cg < 4; ++cg)
#pragma unroll
            for (int r = 0; r < 4; ++r) {
                float v = acc[cg][r] + biasv[cg];
                pi[r] = fmaf(v, aiv[cg], pi[r]);
                pj[r] = fmaf(v, ajv[cg], pj[r]);
                tp[(quad * 4 + r) * 72 + cg * 16 + col0] = __float2bfloat16(v);
            }
        __asm__ __volatile__("s_waitcnt lgkmcnt(0)" ::: "memory");
        int rr = lane >> 2, hh = lane & 3;
        int orow = n0 + rr;
        if (orow < N) {
            const float4* sp = (const float4*)(tp + rr * 72 + hh * 16);
            float4 v0 = sp[0], v1 = sp[1];
            float4* gp = (float4*)(xlb + (size_t)orow * CO + hh * 16);
            gp[0] = v0; gp[1] = v1;
        }
#pragma unroll
        for (int r = 0; r < 4; ++r)
#pragma unroll
            for (int off = 1; off < 16; off <<= 1) {
                pi[r] += __shfl_xor(pi[r], off);
                pj[r] += __shfl_xor(pj[r], off);
            }
        if (col0 == 0) {
#pragma unroll
            for (int r = 0; r < 4; ++r) {
                int n = n0 + quad * 4 + r;
                if (n < N) {
                    s_i[n] = sie[n] + pi[r];
                    s_j[n] = sje[n] + pj[r];
                }
            }
        }
    }
}

#define BIN_CHUNK 8192
// K2a: bucket histogram (bucket = dst>>7). One global atomic per (block,bucket).
__global__ __launch_bounds__(256) void k_bhist(const int* __restrict__ dst, int E,
                                               int* __restrict__ bcnt)
{
    __shared__ int h[1024];
    int base = blockIdx.x * BIN_CHUNK;
    int cnt  = min(BIN_CHUNK, E - base);
    for (int i = threadIdx.x; i < 1024; i += 256) h[i] = 0;
    __syncthreads();
    for (int k = threadIdx.x; k < cnt; k += 256) atomicAdd(&h[dst[base + k] >> 7], 1);
    __syncthreads();
    for (int i = threadIdx.x; i < 1024; i += 256)
        if (h[i]) atomicAdd(&bcnt[i], h[i]);
}

// K2b: single-block exclusive scan of 1024 bucket counts -> bucket edge bases
__global__ __launch_bounds__(1024) void k_bscan(const int* __restrict__ bcnt,
                                                int* __restrict__ bbase)
{
    __shared__ int s[1024];
    int t = threadIdx.x;
    int v = bcnt[t];
    s[t] = v;
    __syncthreads();
    for (int off = 1; off < 1024; off <<= 1) {
        int y = (t >= off) ? s[t - off] : 0;
        __syncthreads();
        s[t] += y;
        __syncthreads();
    }
    bbase[t] = s[t] - v;                          // exclusive
}

// K3a: bucket-partition edges into ebuf (packed src | doff<<17), block-local runs.
__global__ __launch_bounds__(256) void k_binA(
    const int* __restrict__ src, const int* __restrict__ dst, int E,
    const int* __restrict__ bbase, int* __restrict__ gcur, unsigned* __restrict__ ebuf)
{
    __shared__ unsigned hist[1024];
    __shared__ unsigned gstart[1024];
    int base = blockIdx.x * BIN_CHUNK;
    int cnt  = min(BIN_CHUNK, E - base);
    for (int b = threadIdx.x; b < 1024; b += 256) hist[b] = 0;
    __syncthreads();
    for (int k = threadIdx.x; k < cnt; k += 256) {
        int d = dst[base + k];
        atomicAdd(&hist[d >> 7], 1u);
    }
    __syncthreads();
    for (int b = threadIdx.x; b < 1024; b += 256) {
        unsigned c = hist[b];
        if (c) gstart[b] = (unsigned)bbase[b] + (unsigned)atomicAdd(&gcur[b], (int)c);
        hist[b] = 0;                              // reuse as local cursor
    }
    __syncthreads();
    for (int k = threadIdx.x; k < cnt; k += 256) {
        int s = src[base + k];
        int d = dst[base + k];
        int b = d >> 7;
        unsigned packed = (unsigned)s | ((unsigned)(d & 127) << 17);
        unsigned pos = gstart[b] + atomicAdd(&hist[b], 1u);
        ebuf[pos] = packed;
    }
}

// K3b: per bucket: degree hist + scan -> CSR row (direct write), counting-sort srcs.
__global__ __launch_bounds__(256) void k_binB(
    const int* __restrict__ bbase, const unsigned* __restrict__ ebuf,
    int* __restrict__ row, int* __restrict__ ssort, int N, int E, int NBUK)
{
    __shared__ int h[128];
    __shared__ int sc[128];
    __shared__ int lrow[128];
    __shared__ int lcur[128];
    int b = blockIdx.x;
    int start = b << 7;
    int sz = min(128, N - start);
    int eb   = bbase[b];
    int cntB = bbase[b + 1] - eb;
    int t = threadIdx.x;
    if (t < 128) { h[t] = 0; lcur[t] = 0; }
    __syncthreads();
    for (int k = t; k < cntB; k += 256) atomicAdd(&h[ebuf[eb + k] >> 17], 1);
    __syncthreads();
    if (t < 128) sc[t] = h[t];
    __syncthreads();
    for (int off = 1; off < 128; off <<= 1) {
        int y = (t >= off && t < 128) ? sc[t - off] : 0;
        __syncthreads();
        if (t < 128) sc[t] += y;
        __syncthreads();
    }
    if (t < sz) {
        int r = eb + (sc[t] - h[t]) + start + t;  // edges_before + self_slots_before
        lrow[t] = r;
        row[start + t] = r;
    }
    if (b == NBUK - 1 && t == 0) row[N] = E + N;
    __syncthreads();
    for (int k = t; k < cntB; k += 256) {
        unsigned e = ebuf[eb + k];
        int doff = (int)(e >> 17);
        int s    = (int)(e & 0x1FFFFu);
        int p = atomicAdd(&lcur[doff], 1);
        ssort[lrow[doff] + p] = s;
    }
}

// K5: softmax + aggregation. HALF-WAVE per node: 2 nodes/wave, lane = 2 channels via
// packed bfloat162 — halves the redundant per-edge scalar work (gather idx, s_j, exp)
// vs full-wave. BN partials staged in LDS: one global atomic set per BLOCK (8 nodes).
__global__ __launch_bounds__(256) void k_agg(
    const unsigned* __restrict__ xp,              // xlb as packed bfloat162[N*32]
    const float* __restrict__ s_i, const float* __restrict__ s_j,
    const int* __restrict__ row, const int* __restrict__ ssort,
    const float* __restrict__ bias, int N,
    float* __restrict__ outp, float2* __restrict__ pd,
    float* __restrict__ spread)
{
    __shared__ float bsm[64];
    __shared__ float bsq[64];
    int t = threadIdx.x;
    if (t < 64) { bsm[t] = 0.f; bsq[t] = 0.f; }
    __syncthreads();

    int lane = t & 63;
    int wv   = t >> 6;
    int half = lane >> 5;
    int l32  = lane & 31;
    int n    = blockIdx.x * 8 + wv * 2 + half;
    bool nv  = (n < N);
    int nn   = nv ? n : (N - 1);

    int r0 = row[nn], r1 = row[nn + 1];
    int cntE = r1 - r0 - 1;                       // real in-edges (self slot at end)
    float si_n  = s_i[nn];
    float eself = __expf(lrelu(si_n + s_j[nn], 0.2f));
    float den = eself;
    float2 xself = bf2x(xp[(size_t)nn * 32 + l32]);
    float acc0 = eself * xself.x, acc1 = eself * xself.y;

    int cntO = __shfl_xor(cntE, 32);              // other half's count
    int kmin = min(cntE, cntO) & ~7;
    int kmax = max(cntE, cntO);

    int k = 0;
    for (; k < kmin; k += 8) {                    // both halves full: no predication
        const int* sp = ssort + r0 + k;
        int sv[8];
#pragma unroll
        for (int u = 0; u < 8; ++u) sv[u] = sp[u];
        float sjv[8];
#pragma unroll
        for (int u = 0; u < 8; ++u) sjv[u] = s_j[sv[u]];
        unsigned pk[8];
#pragma unroll
        for (int u = 0; u < 8; ++u) pk[u] = xp[(size_t)sv[u] * 32 + l32];
#pragma unroll
        for (int u = 0; u < 8; ++u) {
            float e = __expf(lrelu(si_n + sjv[u], 0.2f));
            den += e;
            float2 xv = bf2x(pk[u]);
            acc0 = fmaf(e, xv.x, acc0);
            acc1 = fmaf(e, xv.y, acc1);
        }
    }
    for (; k < kmax; ++k) {                       // divergent tail, predicated per half
        bool v = k < cntE;
        int s = v ? ssort[r0 + k] : nn;
        float e = v ? __expf(lrelu(si_n + s_j[s], 0.2f)) : 0.f;
        den += e;
        float2 xv = bf2x(xp[(size_t)s * 32 + l32]);
        acc0 = fmaf(e, xv.x, acc0);
        acc1 = fmaf(e, xv.y, acc1);
    }

    float inv = 1.0f / den;
    int c0 = l32 * 2;
    float v0 = acc0 * inv + bias[c0];
    float v1 = acc1 * inv + bias[c0 + 1];
    if (nv) {
        ((float2*)(outp + (size_t)n * CO))[l32] = make_float2(v0, v1);
        if (l32 == 0) pd[n] = make_float2(si_n, inv);
        atomicAdd(&bsm[c0],     v0);
        atomicAdd(&bsm[c0 + 1], v1);
        atomicAdd(&bsq[c0],     v0 * v0);
        atomicAdd(&bsq[c0 + 1], v1 * v1);
    }
    __syncthreads();
    if (t < 64) {
        int slot = blockIdx.x & 255;
        atomicAdd(&spread[slot * 128 + t],      bsm[t]);
        atomicAdd(&spread[slot * 128 + 64 + t], bsq[t]);
    }
}

// K6: att_weight in ORIGINAL edge order (E real edges then N self-loops).
__global__ void k_att(const int* __restrict__ src, const int* __restrict__ dst, int E, int N,
                      const float2* __restrict__ pd, const float* __restrict__ s_j,
                      float* __restrict__ att)
{
    int i = blockIdx.x * 256 + threadIdx.x;
    int tot = E + N;
    if (i >= tot) return;
    int s, d;
    if (i < E) { s = src[i]; d = dst[i]; } else { s = d = i - E; }
    float2 p = pd[d];
    float a = lrelu(p.x + s_j[s], 0.2f);
    att[i] = __expf(a) * p.y;
}

// K7: reduce BN partials -> per-channel scale/shift
__global__ __launch_bounds__(1024) void k_bnstats(const float* __restrict__ spread, int N,
    const float* __restrict__ gamma, const float* __restrict__ beta,
    float* __restrict__ scale, float* __restrict__ shift)
{
    __shared__ float red[8][128];
    __shared__ float tot[128];
    int c = threadIdx.x & 127;
    int p = threadIdx.x >> 7;
    float a = 0.f;
    for (int s = p; s < 256; s += 8) a += spread[s * 128 + c];
    red[p][c] = a;
    __syncthreads();
    if (threadIdx.x < 128) {
        float t = 0.f;
        for (int q = 0; q < 8; ++q) t += red[q][c];
        tot[c] = t;
    }
    __syncthreads();
    if (threadIdx.x < 64) {
        float inv = 1.f / (float)N;
        float mu  = tot[threadIdx.x] * inv;
        float msq = tot[64 + threadIdx.x] * inv;
        float var = msq - mu * mu;
        float sc  = gamma[threadIdx.x] * rsqrtf(var + 1e-5f);
        scale[threadIdx.x] = sc;
        shift[threadIdx.x] = beta[threadIdx.x] - mu * sc;
    }
}

// K8: in-place BN + leaky(0.01) epilogue, float4-vectorized
__global__ void k_bnapply(float* __restrict__ outp, int N,
                          const float* __restrict__ scale, const float* __restrict__ shift)
{
    int i = blockIdx.x * 256 + threadIdx.x;
    int tot = N * CO / 4;
    if (i >= tot) return;
    float4 v = ((float4*)outp)[i];
    int c0 = (i * 4) & (CO - 1);
    v.x = lrelu(fmaf(scale[c0 + 0], v.x, shift[c0 + 0]), 0.01f);
    v.y = lrelu(fmaf(scale[c0 + 1], v.y, shift[c0 + 1]), 0.01f);
    v.z = lrelu(fmaf(scale[c0 + 2], v.z, shift[c0 + 2]), 0.01f);
    v.w = lrelu(fmaf(scale[c0 + 3], v.w, shift[c0 + 3]), 0.01f);
    ((float4*)outp)[i] = v;
}

extern "C" void kernel_launch(void* const* d_in, const int* in_sizes, int n_in,
                              void* d_out, int out_size, void* d_ws, size_t ws_size,
                              hipStream_t stream)
{
    const float* x    = (const float*)d_in[0];
    const int*   ei   = (const int*)  d_in[1];
    const float* emb  = (const float*)d_in[2];
    const float* W    = (const float*)d_in[3];
    const float* lb   = (const float*)d_in[4];
    const float* ai   = (const float*)d_in[5];
    const float* aj   = (const float*)d_in[6];
    const float* aei  = (const float*)d_in[7];
    const float* aej  = (const float*)d_in[8];
    const float* bias = (const float*)d_in[9];
    const float* gam  = (const float*)d_in[10];
    const float* bet  = (const float*)d_in[11];

    int N = in_sizes[0] / CIN;
    int E = in_sizes[1] / 2;
    const int* srcv = ei;
    const int* dstv = ei + E;
    int NBUK = (N + 127) >> 7;

    float* ws = (float*)d_ws;
    size_t o = 0;
    __hip_bfloat16* xlb = (__hip_bfloat16*)(ws + o); o += (size_t)N * CO / 2;
    float* s_i   = ws + o; o += N;
    float* s_j   = ws + o; o += N;
    float* sie   = ws + o; o += N;
    float* sje   = ws + o; o += N;
    float2* pd   = (float2*)(ws + o); o += 2 * (size_t)N;
    int*   row   = (int*)(ws + o); o += (size_t)N + 1;
    o += (o & 1);                                   // even-align
    int*   bbase = (int*)(ws + o); o += 1024;
    size_t zoff  = o;                               // ---- zeroed region start ----
    int*   bcnt  = (int*)(ws + o); o += 1024;
    int*   gcur  = (int*)(ws + o); o += 1024;
    float* spread= ws + o;         o += 256 * 128;
    size_t zbytes = (o - zoff) * sizeof(float);     // ---- zeroed region end ----
    float* scale = ws + o; o += CO;
    float* shift = ws + o; o += CO;
    unsigned* ebuf = (unsigned*)(ws + o); o += E;
    int*   ssort = (int*)(ws + o); o += (size_t)E + N;   // slot space includes self gaps

    float* out_nodes = (float*)d_out;
    float* out_att   = out_nodes + (size_t)N * CO;

    hipMemsetAsync((void*)bcnt, 0, zbytes, stream);

    int CHB = (E + BIN_CHUNK - 1) / BIN_CHUNK;
    k_escore<<<1024, 256, 0, stream>>>(emb, aei, aej, sie, sje, N);
    k_gemm<<<512, 256, 0, stream>>>(x, W, lb, ai, aj, sie, sje, xlb, s_i, s_j, N);
    k_bhist<<<CHB, 256, 0, stream>>>(dstv, E, bcnt);
    k_bscan<<<1, 1024, 0, stream>>>(bcnt, bbase);
    k_binA<<<CHB, 256, 0, stream>>>(srcv, dstv, E, bbase, gcur, ebuf);
    k_binB<<<NBUK, 256, 0, stream>>>(bbase, ebuf, row, ssort, N, E, NBUK);
    k_agg<<<(N + 7) / 8, 256, 0, stream>>>((const unsigned*)xlb, s_i, s_j, row, ssort, bias, N,
                                           out_nodes, pd, spread);
    k_att<<<(E + N + 255) / 256, 256, 0, stream>>>(srcv, dstv, E, N, pd, s_j, out_att);
    k_bnstats<<<1, 1024, 0, stream>>>(spread, N, gam, bet, scale, shift);
    k_bnapply<<<((N * CO / 4) + 255) / 256, 256, 0, stream>>>(out_nodes, N, scale, shift);
}